// Round 16
// baseline (141.362 us; speedup 1.0000x reference)
//
#include <hip/hip_runtime.h>
#include <stdint.h>

#define Bsz 16384
#define Hh  512
#define Kd  1024      // I + H
#define BM  128       // M rows per workgroup
#define BNJ 32        // j columns per workgroup (x5 gates)
#define NT  32        // K tiles of 32 (2 k-steps of 16)

// LDS buffer: A 8KB + B 10KB = 18KB; two buffers = 36KB -> 3 wg/CU
#define BUFB 18432

typedef __attribute__((ext_vector_type(8))) short bf16x8;
typedef __attribute__((ext_vector_type(16))) float f32x16;
typedef __attribute__((ext_vector_type(8))) unsigned short u16x8;

__device__ __forceinline__ unsigned short f2bf(float f) {
    union { float f; unsigned u; } v; v.f = f;
    unsigned u = v.u;
    return (unsigned short)((u + 0x7fffu + ((u >> 16) & 1u)) >> 16);
}
__device__ __forceinline__ float fast_tanh(float x) {
    float e = __expf(2.f * x);
    return (e - 1.f) / (e + 1.f);
}
__device__ __forceinline__ float fast_sigmoid(float x) {
    return 1.f / (1.f + __expf(-x));
}

// ---- pack A fragment-linear for 32x32x16: blk = (mblk*64 + kt)*4 + u ----
// elem blk*512 + l*8 + e = A[mblk*128 + u*32 + (l&31)][kt*16 + (l>>5)*8 + e]
// A[r][k] = x[r][k] (k<512) else h_prev[r][k-512]
__global__ void pack_A(const float* __restrict__ x, const float* __restrict__ h,
                       unsigned short* __restrict__ A) {
    const long total = (long)Bsz * Kd / 8;   // 2,097,152 units of 8
    for (long i = (long)blockIdx.x * blockDim.x + threadIdx.x; i < total;
         i += (long)gridDim.x * blockDim.x) {
        int  l    = (int)(i & 63);
        long blk  = i >> 6;
        int  u    = (int)(blk & 3);
        int  kt   = (int)((blk >> 2) & 63);
        long mblk = blk >> 8;
        long row  = mblk * 128 + u * 32 + (l & 31);
        int  k0   = kt * 16 + ((l >> 5) << 3);
        const float* src = (k0 < 512) ? (x + row * 512 + k0)
                                      : (h + row * 512 + (k0 - 512));
        float4 f0 = *(const float4*)(src);
        float4 f1 = *(const float4*)(src + 4);
        u16x8 o;
        o[0]=f2bf(f0.x); o[1]=f2bf(f0.y); o[2]=f2bf(f0.z); o[3]=f2bf(f0.w);
        o[4]=f2bf(f1.x); o[5]=f2bf(f1.y); o[6]=f2bf(f1.z); o[7]=f2bf(f1.w);
        *(u16x8*)(A + (i << 3)) = o;
    }
}

// ---- pack B fragment-linear for 32x32x16: blk = (jgrp*5 + g)*64 + kt ----
// elem blk*512 + l*8 + e = W[g][ jgrp*32 + (l&31) ][ kt*16 + (l>>5)*8 + e ]
__global__ void pack_B(const float* __restrict__ Wxi, const float* __restrict__ Whi,
                       const float* __restrict__ Wxf, const float* __restrict__ Whf,
                       const float* __restrict__ Wxc, const float* __restrict__ Whc,
                       const float* __restrict__ Wxo, const float* __restrict__ Who,
                       const float* __restrict__ We,
                       const float* __restrict__ bxi, const float* __restrict__ bhi,
                       const float* __restrict__ bxf, const float* __restrict__ bhf,
                       const float* __restrict__ bxc, const float* __restrict__ bhc,
                       const float* __restrict__ bxo, const float* __restrict__ bho,
                       const float* __restrict__ be,
                       unsigned short* __restrict__ Bp, float* __restrict__ bias) {
    const long id = (long)blockIdx.x * blockDim.x + threadIdx.x;  // 327680 total
    if (id < 327680) {
        int blk = (int)(id >> 6);
        int l   = (int)(id & 63);
        int kt  = blk & 63;
        int rest = blk >> 6;
        int g    = rest % 5;
        int jgrp = rest / 5;      // 0..15 (32-j groups)
        int j  = jgrp * 32 + (l & 31);
        int k0 = kt * 16 + ((l >> 5) << 3);
        const float* src;
        if (g == 4) {
            src = We + (long)j * 1024 + k0;
        } else {
            const float* Wx = (g == 0) ? Wxi : (g == 1) ? Wxf : (g == 2) ? Wxc : Wxo;
            const float* Wh = (g == 0) ? Whi : (g == 1) ? Whf : (g == 2) ? Whc : Who;
            src = (k0 < 512) ? (Wx + (long)j * 512 + k0)
                             : (Wh + (long)j * 512 + (k0 - 512));
        }
        float4 f0 = *(const float4*)(src);
        float4 f1 = *(const float4*)(src + 4);
        u16x8 o;
        o[0]=f2bf(f0.x); o[1]=f2bf(f0.y); o[2]=f2bf(f0.z); o[3]=f2bf(f0.w);
        o[4]=f2bf(f1.x); o[5]=f2bf(f1.y); o[6]=f2bf(f1.z); o[7]=f2bf(f1.w);
        *(u16x8*)(Bp + (long)blk * 512 + l * 8) = o;
    }
    if (id < 2560) {
        int row = (int)id;
        int g = row >> 9, j = row & 511;
        float b;
        if (g == 4) b = be[j];
        else {
            const float* bx = (g == 0) ? bxi : (g == 1) ? bxf : (g == 2) ? bxc : bxo;
            const float* bh = (g == 0) ? bhi : (g == 1) ? bhf : (g == 2) ? bhc : bho;
            b = bx[j] + bh[j];
        }
        bias[row] = b;
    }
}

// ---- fused GEMM: 32x32x16 MFMA, R8 skeleton (2 bufs, 1 barrier/tile, 3 wg/CU) ----
#define GL16(g, l) __builtin_amdgcn_global_load_lds( \
    (const __attribute__((address_space(1))) unsigned int*)(g), \
    (__attribute__((address_space(3))) unsigned int*)(l), 16, 0, 0)

#define VM0()      asm volatile("s_waitcnt vmcnt(0)" ::: "memory")
#define BARRIER()  asm volatile("s_barrier" ::: "memory")

#define MF32(a, b, c) __builtin_amdgcn_mfma_f32_32x32x16_bf16(a, b, c, 0, 0, 0)

// k-step 0 reads: A frag (wave's wm unit) + 5 B frags
#define RDK0(RBO) do { \
    af0 = *(const bf16x8*)(aRP + (RBO)); \
    b0  = *(const bf16x8*)(bRP + (RBO) + 0 * 1024); \
    b1  = *(const bf16x8*)(bRP + (RBO) + 1 * 1024); \
    b2  = *(const bf16x8*)(bRP + (RBO) + 2 * 1024); \
    b3  = *(const bf16x8*)(bRP + (RBO) + 3 * 1024); \
    b4  = *(const bf16x8*)(bRP + (RBO) + 4 * 1024); \
} while (0)
// k-step 1 reads
#define RDK1(RBO) do { \
    af1 = *(const bf16x8*)(aRP + (RBO) + 4096); \
    b5  = *(const bf16x8*)(bRP + (RBO) + 5120 + 0 * 1024); \
    b6  = *(const bf16x8*)(bRP + (RBO) + 5120 + 1 * 1024); \
    b7  = *(const bf16x8*)(bRP + (RBO) + 5120 + 2 * 1024); \
    b8  = *(const bf16x8*)(bRP + (RBO) + 5120 + 3 * 1024); \
    b9  = *(const bf16x8*)(bRP + (RBO) + 5120 + 4 * 1024); \
} while (0)

#define MFMA5A() do { \
    __builtin_amdgcn_s_setprio(1); \
    acc[0] = MF32(af0, b0, acc[0]); \
    acc[1] = MF32(af0, b1, acc[1]); \
    acc[2] = MF32(af0, b2, acc[2]); \
    acc[3] = MF32(af0, b3, acc[3]); \
    acc[4] = MF32(af0, b4, acc[4]); \
    __builtin_amdgcn_s_setprio(0); \
} while (0)
#define MFMA5B() do { \
    __builtin_amdgcn_s_setprio(1); \
    acc[0] = MF32(af1, b5, acc[0]); \
    acc[1] = MF32(af1, b6, acc[1]); \
    acc[2] = MF32(af1, b7, acc[2]); \
    acc[3] = MF32(af1, b8, acc[3]); \
    acc[4] = MF32(af1, b9, acc[4]); \
    __builtin_amdgcn_s_setprio(0); \
} while (0)

// stage tile T into buffer at byte SO: 2 A-chunks + 3 B-units per thread
#define SG5(SO, T) do { \
    GL16(asg0 + (T) * 4096, lds_raw + (SO) + adst0); \
    GL16(asg1 + (T) * 4096, lds_raw + (SO) + adst1); \
    GL16(bsg0 + (T) * 1024, lds_raw + (SO) + bdo0); \
    GL16(bsg1 + (T) * 1024, lds_raw + (SO) + bdo1); \
    GL16(bsg2 + (T) * 1024, lds_raw + (SO) + bdo2); \
} while (0)

// one K32-tile: stage T+1, read 12 frags, 2x5 MFMA32, certify + barrier
#define TILE(RBO, SBO, T, STG, SYNC) do { \
    if (STG) SG5(SBO, (T) + 1); \
    RDK0(RBO); RDK1(RBO); \
    MFMA5A(); \
    MFMA5B(); \
    if (SYNC) { VM0(); BARRIER(); } \
} while (0)

__global__ __launch_bounds__(256, 3)
void xlstm_gemm(const unsigned short* __restrict__ Apk,
                const unsigned short* __restrict__ Bp,
                const float* __restrict__ bias,
                const float* __restrict__ c_prev,
                float* __restrict__ out) {
    __shared__ __align__(16) unsigned char lds_raw[2 * BUFB];  // 36 KB

    const int tid  = threadIdx.x;
    const int wid  = tid >> 6;    // 0..3 : wm (32-row group)
    const int lane = tid & 63;
    const int wm   = wid;
    const int jl   = lane & 31;
    const int q5   = lane >> 5;

    // T1: bijective XCD swizzle (nwg = 2048, 2048 % 8 == 0)
    const int orig = blockIdx.x;
    const int wg   = (orig & 7) * 256 + (orig >> 3);
    const int mblk = wg >> 4;     // 0..127
    const int jblk = wg & 15;     // 0..15
    const long brow = (long)mblk * BM;
    const int  bcol = jblk * BNJ;

    f32x16 acc[5];
#pragma unroll
    for (int g = 0; g < 5; ++g)
#pragma unroll
        for (int r = 0; r < 16; ++r) acc[g][r] = 0.f;

    bf16x8 af0, af1, b0, b1, b2, b3, b4, b5, b6, b7, b8, b9;

    // ---- read-side LDS pointers ----
    // A unit (ks, wm) at ks*4096 + wm*1024; B unit (ks, g) at 8192 + ks*5120 + g*1024
    const unsigned char* aRP = lds_raw + wm * 1024 + lane * 16;
    const unsigned char* bRP = lds_raw + 8192 + lane * 16;

    // ---- staging pointers ----
    // A tile T = 4096 elems (8 KB) at elem offset mblk*131072 + T*4096
    // (pack per-mblk stride = 128 rows x 1024 k = 131072 ELEMENTS — R15 bug was 2x this)
    const unsigned short* asg0 = Apk + (long)mblk * 131072 + tid * 8;
    const unsigned short* asg1 = asg0 + 2048;
    const int adst0 = tid * 16;
    const int adst1 = 4096 + tid * 16;
    // B: unit u = wid + 4i (i<3), u>=10 wraps (benign dup); u = ks*5 + g
    const unsigned short *bsg0, *bsg1, *bsg2;
    int bdo0, bdo1, bdo2;
#define BSTG_INIT(i) do { \
    int u_ = wid + 4 * (i); if (u_ >= 10) u_ -= 10; \
    int ks_ = u_ / 5; int g_ = u_ - 5 * ks_; \
    bsg##i = Bp + ((long)(jblk * 5 + g_) * 64 + ks_) * 512 + lane * 8; \
    bdo##i = 8192 + u_ * 1024 + lane * 16; \
} while (0)
    BSTG_INIT(0); BSTG_INIT(1); BSTG_INIT(2);
#undef BSTG_INIT

    // ---- prologue: stage tile 0 into buf0, certify ----
    SG5(0, 0);
    VM0();
    BARRIER();

    // ---- main loop: tile t reads buf t&1, stages t+1 into buf^1 ----
    for (int t = 0; t < 30; t += 2) {
        TILE(0,    BUFB, t,     1, 1);
        TILE(BUFB, 0,    t + 1, 1, 1);
    }
    TILE(0,    BUFB, 30, 1, 1);
    TILE(BUFB, 0,    31, 0, 0);

    // ---------------- epilogue (fused, in-register; 32x32 C/D layout) ----------------
    // col = lane&31, row = (r&3) + 8*(r>>2) + 4*(lane>>5)   [m74/m101-verified]
    const int j = bcol + jl;
    const float bi_ = bias[j];
    const float bf_ = bias[512 + j];
    const float bc_ = bias[1024 + j];
    const float bo_ = bias[1536 + j];
    const float be_ = bias[2048 + j];
    const long rbase = brow + wm * 32 + 4 * q5;
#pragma unroll
    for (int r = 0; r < 16; ++r) {
        long row = rbase + (r & 3) + 8 * (r >> 2);
        float gi = acc[0][r] + bi_;
        float gf = acc[1][r] + bf_;
        float gc = acc[2][r] + bc_;
        float go = acc[3][r] + bo_;
        float ge = acc[4][r] + be_;
        float iv = fast_sigmoid(gi);
        float fv = fast_sigmoid(gf);
        float gv = fast_tanh(gc);
        float ov = fast_sigmoid(go);
        float ef = __expf(fast_tanh(ge));
        float cp = c_prev[row * 512 + j];
        float cv = fv * cp + iv * gv;
        float hv = ov * fast_tanh(cv) * ef;
        out[row * 512 + j] = hv;
        out[(long)Bsz * 512 + row * 512 + j] = cv;
    }
}

extern "C" void kernel_launch(void* const* d_in, const int* in_sizes, int n_in,
                              void* d_out, int out_size, void* d_ws, size_t ws_size,
                              hipStream_t stream) {
    const float* x      = (const float*)d_in[0];
    const float* h_prev = (const float*)d_in[1];
    const float* c_prev = (const float*)d_in[2];
    const float* Wxi = (const float*)d_in[3];
    const float* bxi = (const float*)d_in[4];
    const float* Whi = (const float*)d_in[5];
    const float* bhi = (const float*)d_in[6];
    const float* Wxf = (const float*)d_in[7];
    const float* bxf = (const float*)d_in[8];
    const float* Whf = (const float*)d_in[9];
    const float* bhf = (const float*)d_in[10];
    const float* Wxc = (const float*)d_in[11];
    const float* bxc = (const float*)d_in[12];
    const float* Whc = (const float*)d_in[13];
    const float* bhc = (const float*)d_in[14];
    const float* Wxo = (const float*)d_in[15];
    const float* bxo = (const float*)d_in[16];
    const float* Who = (const float*)d_in[17];
    const float* bho = (const float*)d_in[18];
    const float* We  = (const float*)d_in[19];
    const float* be  = (const float*)d_in[20];

    unsigned short* Abf  = (unsigned short*)d_ws;                        // 33,554,432 B
    unsigned short* Bp   = (unsigned short*)((char*)d_ws + 33554432);    //  5,242,880 B
    float*          bias = (float*)((char*)d_ws + 33554432 + 5242880);   //     10,240 B

    pack_A<<<2048, 256, 0, stream>>>(x, h_prev, Abf);
    pack_B<<<1280, 256, 0, stream>>>(Wxi, Whi, Wxf, Whf, Wxc, Whc, Wxo, Who, We,
                                     bxi, bhi, bxf, bhf, bxc, bhc, bxo, bho, be,
                                     Bp, bias);
    xlstm_gemm<<<2048, 256, 0, stream>>>(Abf, Bp, bias, c_prev, (float*)d_out);
}